// Round 5
// baseline (1368.174 us; speedup 1.0000x reference)
//
#include <hip/hip_runtime.h>
#include <hip/hip_bf16.h>

#define N_NODES  60000
#define N_EDGES  240000
#define N_REL    4
#define N_GRAPHS 128
#define D_IN     768
#define D_H      256
#define N_LAYERS 6
#define M_PAD    60032            // 469 * 128
#define N_TOT    1280             // L0: 256 root + 4*256 msg
#define BM_L     64               // fused layer: dst rows per block
#define LDM      264              // mean tile row stride (+16B pad -> 4-bank stagger)

static inline int cdiv(int a, int b) { return (a + b - 1) / b; }

typedef __attribute__((ext_vector_type(8))) short short8;
typedef __attribute__((ext_vector_type(4))) float f32x4;

__device__ __forceinline__ float bf2f(unsigned short u) {
    union { unsigned int i; float f; } c; c.i = ((unsigned int)u) << 16; return c.f;
}
__device__ __forceinline__ float bflo(unsigned int u) {
    union { unsigned int i; float f; } c; c.i = u << 16; return c.f;
}
__device__ __forceinline__ float bfhi(unsigned int u) {
    union { unsigned int i; float f; } c; c.i = u & 0xffff0000u; return c.f;
}
__device__ __forceinline__ unsigned short f2bf(float f) {
    union { float f; unsigned int i; } c; c.f = f;
    unsigned int i = c.i;
    unsigned int r = (i + 0x7FFFu + ((i >> 16) & 1u)) >> 16;   // RNE
    return (unsigned short)r;
}

__device__ __forceinline__ void gload16(const void* g, void* l) {
    __builtin_amdgcn_global_load_lds((const __attribute__((address_space(1))) void*)g,
                                     (__attribute__((address_space(3))) void*)l, 16, 0, 0);
}

__device__ __forceinline__ void accum32(float4* am, uint4 v0, uint4 v1, uint4 v2, uint4 v3) {
    am[0].x += bflo(v0.x); am[0].y += bfhi(v0.x);
    am[0].z += bflo(v0.y); am[0].w += bfhi(v0.y);
    am[1].x += bflo(v0.z); am[1].y += bfhi(v0.z);
    am[1].z += bflo(v0.w); am[1].w += bfhi(v0.w);
    am[2].x += bflo(v1.x); am[2].y += bfhi(v1.x);
    am[2].z += bflo(v1.y); am[2].w += bfhi(v1.y);
    am[3].x += bflo(v1.z); am[3].y += bfhi(v1.z);
    am[3].z += bflo(v1.w); am[3].w += bfhi(v1.w);
    am[4].x += bflo(v2.x); am[4].y += bfhi(v2.x);
    am[4].z += bflo(v2.y); am[4].w += bfhi(v2.y);
    am[5].x += bflo(v2.z); am[5].y += bfhi(v2.z);
    am[5].z += bflo(v2.w); am[5].w += bfhi(v2.w);
    am[6].x += bflo(v3.x); am[6].y += bfhi(v3.x);
    am[6].z += bflo(v3.y); am[6].w += bfhi(v3.y);
    am[7].x += bflo(v3.z); am[7].y += bfhi(v3.z);
    am[7].z += bflo(v3.w); am[7].w += bfhi(v3.w);
}

// ---------------------------------------------------------------------------
// Layer-0 GEMM (transform-first): A[M_PAD,768] bf16 @ Wt0[1280,768]^T.
// Flat grid, XCD-swizzled: a row-block's 5 col-blocks share b%8 -> same XCD
// -> A row-slice fetched ~once per XCD L2.
// ---------------------------------------------------------------------------
__global__ __launch_bounds__(512) void gemm_l0(
    const unsigned short* __restrict__ A,
    const unsigned short* __restrict__ Bt,
    const float* __restrict__ bias,
    unsigned short* __restrict__ out_root,
    unsigned short* __restrict__ out_msg,
    int K)
{
    __shared__ unsigned short As[128 * 32];
    __shared__ unsigned short Bs[256 * 32];

    const int tid  = threadIdx.x;
    const int wave = tid >> 6, lane = tid & 63;

    // XCD swizzle: 58 groups of (8 rows x 5 cols) + tail (5 rows x 5 cols)
    int b = blockIdx.x;
    int bm, bn;
    if (b < 2320) { int grp = b / 40, rem = b % 40; bm = (grp * 8 + (rem & 7)) * 128; bn = (rem >> 3) * 256; }
    else          { int rem = b - 2320; bm = (464 + rem % 5) * 128; bn = (rem / 5) * 256; }

    const int wm = (wave & 1) * 64, wn = (wave >> 1) * 64;

    const int lr = lane >> 2;
    const int kg = ((lane & 3) ^ ((lr ^ (lr >> 2)) & 3)) * 8;   // swizzled k-chunk
    const unsigned short* gsrc[3];
    unsigned short* ldst[3];
    #pragma unroll
    for (int j = 0; j < 3; ++j) {
        int g = wave * 3 + j;
        if (g < 8) {
            gsrc[j] = A + (size_t)(bm + g * 16 + lr) * K + kg;
            ldst[j] = As + g * 16 * 32;
        } else {
            gsrc[j] = Bt + (size_t)(bn + (g - 8) * 16 + lr) * K + kg;
            ldst[j] = Bs + (g - 8) * 16 * 32;
        }
    }

    f32x4 acc[4][4] = {};
    const int fr = lane & 15;
    const int qsw = (((lane >> 4) ^ fr ^ (fr >> 2)) & 3) * 8;

    for (int k0 = 0; k0 < K; k0 += 32) {
        gload16(gsrc[0] + k0, ldst[0]);
        gload16(gsrc[1] + k0, ldst[1]);
        gload16(gsrc[2] + k0, ldst[2]);
        __syncthreads();

        short8 a[4], bb[4];
        #pragma unroll
        for (int t = 0; t < 4; ++t) {
            a[t]  = *(const short8*)&As[(wm + t * 16 + fr) * 32 + qsw];
            bb[t] = *(const short8*)&Bs[(wn + t * 16 + fr) * 32 + qsw];
        }
        #pragma unroll
        for (int mt = 0; mt < 4; ++mt)
            #pragma unroll
            for (int nt = 0; nt < 4; ++nt)
                acc[mt][nt] = __builtin_amdgcn_mfma_f32_16x16x32_bf16(
                    a[mt], bb[nt], acc[mt][nt], 0, 0, 0);
        __syncthreads();
    }

    const bool is_root = (bn == 0);   // block-uniform
    #pragma unroll
    for (int mt = 0; mt < 4; ++mt) {
        #pragma unroll
        for (int nt = 0; nt < 4; ++nt) {
            int col = bn + wn + nt * 16 + fr;
            float bv = bias[col];
            #pragma unroll
            for (int r = 0; r < 4; ++r) {
                int row = bm + wm + mt * 16 + ((lane >> 4) << 2) + r;
                float v = acc[mt][nt][r] + bv;
                if (is_root) out_root[(size_t)row * 256 + col] = f2bf(v);
                else         out_msg[(size_t)row * 1024 + (col - 256)] = f2bf(v);
            }
        }
    }
}

// ---------------------------------------------------------------------------
// Fused RGCN mid-layer. Per 64-dst-row block, phases r in {0..3 gather, 4 root}:
// gather h[src] -> fp32 regs -> mean-scale -> bf16 LDS mean-tile; then 8 MFMA
// K-steps with W read DIRECTLY global->VGPR (wave-private rows; W is L2-hot).
// Only 2 barriers per phase (mean tile is the only cross-wave LDS).
// ---------------------------------------------------------------------------
__global__ __launch_bounds__(512) void rgcn_layer(
    const unsigned short* __restrict__ h,     // [M_PAD, 256]
    const unsigned short* __restrict__ Wl,    // [256 out][1280 k]
    const float* __restrict__ bias,           // [256]
    const int* __restrict__ rp4,              // [4*N_NODES + 1]
    const int* __restrict__ e_srcs,           // [E] srcs sorted by (dst, rel)
    const float* __restrict__ inv4,           // [N_NODES*4]
    unsigned short* __restrict__ h_out)       // [M_PAD, 256]
{
    __shared__ unsigned short mt[BM_L * LDM];   // 33,792 B

    const int tid  = threadIdx.x;
    const int wave = tid >> 6, lane = tid & 63;
    const int bm = blockIdx.x * BM_L;

    const int node  = bm + lane;                 // gather: lane = node
    const int cq    = wave * 32;                 // gather: wave = 32-col slice
    const bool valid = node < N_NODES;

    const int fr   = lane & 15;                  // MFMA m / n index
    const int q8   = (lane >> 4) * 8;            // MFMA k offset
    const int wcol = wave * 32;                  // wave's 32 output cols

    // wave-private W row bases (rows wcol+fr and wcol+16+fr)
    const unsigned short* w0p = Wl + (size_t)(wcol + fr) * N_TOT + q8;
    const unsigned short* w1p = Wl + (size_t)(wcol + 16 + fr) * N_TOT + q8;

    float4 iv = valid ? *(const float4*)&inv4[(size_t)node * 4]
                      : make_float4(1.f, 1.f, 1.f, 1.f);

    f32x4 acc[4][2] = {};

    for (int r = 0; r < 5; ++r) {
        float4 am[8];
        #pragma unroll
        for (int j = 0; j < 8; ++j) am[j] = make_float4(0.f, 0.f, 0.f, 0.f);

        if (r < 4) {
            if (valid) {
                int lo = rp4[(size_t)node * 4 + r];
                int hi = rp4[(size_t)node * 4 + r + 1];
                int e = lo;
                for (; e + 1 < hi; e += 2) {
                    const uint4* p0 = (const uint4*)(h + (size_t)e_srcs[e] * 256 + cq);
                    const uint4* p1 = (const uint4*)(h + (size_t)e_srcs[e + 1] * 256 + cq);
                    uint4 v0 = p0[0], v1 = p0[1], v2 = p0[2], v3 = p0[3];
                    uint4 u0 = p1[0], u1 = p1[1], u2 = p1[2], u3 = p1[3];
                    accum32(am, v0, v1, v2, v3);
                    accum32(am, u0, u1, u2, u3);
                }
                if (e < hi) {
                    const uint4* p0 = (const uint4*)(h + (size_t)e_srcs[e] * 256 + cq);
                    accum32(am, p0[0], p0[1], p0[2], p0[3]);
                }
            }
        } else {
            const uint4* p0 = (const uint4*)(h + (size_t)node * 256 + cq);
            accum32(am, p0[0], p0[1], p0[2], p0[3]);
        }
        float sc = (r == 0) ? iv.x : (r == 1) ? iv.y : (r == 2) ? iv.z
                 : (r == 3) ? iv.w : 1.f;

        __syncthreads();   // phase r-1 mt reads complete
        {
            unsigned short* dst = &mt[lane * LDM + cq];
            #pragma unroll
            for (int j = 0; j < 8; ++j) {
                ushort4 o;
                o.x = f2bf(am[j].x * sc); o.y = f2bf(am[j].y * sc);
                o.z = f2bf(am[j].z * sc); o.w = f2bf(am[j].w * sc);
                *(ushort4*)(dst + j * 4) = o;
            }
        }
        __syncthreads();   // mt visible to all waves

        const int rOff = (r << 8);
        #pragma unroll
        for (int kk = 0; kk < 8; ++kk) {
            short8 b0 = *(const short8*)(w0p + rOff + kk * 32);
            short8 b1 = *(const short8*)(w1p + rOff + kk * 32);
            short8 a[4];
            #pragma unroll
            for (int i = 0; i < 4; ++i)
                a[i] = *(const short8*)&mt[(i * 16 + fr) * LDM + kk * 32 + q8];
            #pragma unroll
            for (int i = 0; i < 4; ++i) {
                acc[i][0] = __builtin_amdgcn_mfma_f32_16x16x32_bf16(a[i], b0, acc[i][0], 0, 0, 0);
                acc[i][1] = __builtin_amdgcn_mfma_f32_16x16x32_bf16(a[i], b1, acc[i][1], 0, 0, 0);
            }
        }
    }

    // epilogue: +bias, ReLU, bf16
    #pragma unroll
    for (int i = 0; i < 4; ++i) {
        #pragma unroll
        for (int nt = 0; nt < 2; ++nt) {
            int col = wcol + nt * 16 + fr;
            float bv = bias[col];
            #pragma unroll
            for (int rg = 0; rg < 4; ++rg) {
                int row = bm + i * 16 + ((lane >> 4) << 2) + rg;
                float v = fmaxf(acc[i][nt][rg] + bv, 0.f);
                h_out[(size_t)row * 256 + col] = f2bf(v);
            }
        }
    }
}

// ---------------------------------------------------------------------------
// Prep kernels
// ---------------------------------------------------------------------------
__global__ void convert_x(const float* __restrict__ x, unsigned short* __restrict__ xb) {
    size_t i = ((size_t)blockIdx.x * 256 + threadIdx.x) * 4;
    if (i >= (size_t)M_PAD * D_IN) return;
    ushort4 o;
    if (i < (size_t)N_NODES * D_IN) {
        float4 v = *(const float4*)&x[i];
        o.x = f2bf(v.x); o.y = f2bf(v.y); o.z = f2bf(v.z); o.w = f2bf(v.w);
    } else {
        o.x = o.y = o.z = o.w = 0;
    }
    *(ushort4*)&xb[i] = o;
}

__global__ void pack_w0(const float* __restrict__ root0, const float* __restrict__ w0,
                        unsigned short* __restrict__ Wt0) {
    int idx = blockIdx.x * 256 + threadIdx.x;            // Wt0[n][k], [1280 x 768]
    if (idx >= N_TOT * D_IN) return;
    int k = idx % D_IN, n = idx / D_IN;
    float v = (n < 256) ? root0[k * 256 + n]
                        : w0[(((n >> 8) - 1) * D_IN + k) * 256 + (n & 255)];
    Wt0[idx] = f2bf(v);
}

// WtR[l][n][k]: k<1024 -> w_rest[l][k>>8][k&255][n]; k>=1024 -> root_rest[l][k-1024][n]
__global__ void pack_wr(const float* __restrict__ root_rest, const float* __restrict__ w_rest,
                        unsigned short* __restrict__ WtR) {
    int idx = blockIdx.x * 256 + threadIdx.x;
    if (idx >= 5 * 256 * N_TOT) return;
    int k = idx % N_TOT; int t = idx / N_TOT; int n = t & 255; int l = t >> 8;
    float v = (k < 1024)
        ? w_rest[(((l * 4 + (k >> 8)) * 256) + (k & 255)) * 256 + n]
        : root_rest[(l * 256 + (k - 1024)) * 256 + n];
    WtR[idx] = f2bf(v);
}

__global__ void build_bias(const float* __restrict__ b0, float* __restrict__ eb) {
    int i = blockIdx.x * 256 + threadIdx.x;
    if (i < N_TOT) eb[i] = (i < 256) ? b0[i] : 0.f;
}

// ---------------------------------------------------------------------------
// (dst, rel)-sorted CSR over 4*N segments
// ---------------------------------------------------------------------------
__global__ void deg4_count(const int* __restrict__ dst, const int* __restrict__ rel,
                           int* __restrict__ deg4, int E) {
    int e = blockIdx.x * 256 + threadIdx.x;
    if (e < E) atomicAdd(&deg4[dst[e] * 4 + rel[e]], 1);
}

__global__ void invert4(const int* __restrict__ deg4, float* __restrict__ inv4, int n) {
    int i = blockIdx.x * 256 + threadIdx.x;
    if (i < n) inv4[i] = 1.0f / (float)max(deg4[i], 1);
}

__global__ __launch_bounds__(256) void block_sum(const int* __restrict__ deg,
                                                 int* __restrict__ bsum, int n) {
    __shared__ int s[256];
    int i = blockIdx.x * 256 + threadIdx.x;
    s[threadIdx.x] = (i < n) ? deg[i] : 0;
    __syncthreads();
    for (int o = 128; o > 0; o >>= 1) {
        if (threadIdx.x < o) s[threadIdx.x] += s[threadIdx.x + o];
        __syncthreads();
    }
    if (threadIdx.x == 0) bsum[blockIdx.x] = s[0];
}

__global__ __launch_bounds__(1024) void scan_bsum(const int* __restrict__ bsum,
                                                  int* __restrict__ boff, int nb) {
    __shared__ int s[1024];
    int t = threadIdx.x;
    int v0 = (t < nb) ? bsum[t] : 0;
    s[t] = v0;
    __syncthreads();
    for (int o = 1; o < 1024; o <<= 1) {
        int v = (t >= o) ? s[t - o] : 0;
        __syncthreads();
        s[t] += v;
        __syncthreads();
    }
    if (t < nb) boff[t] = s[t] - v0;   // exclusive
}

__global__ __launch_bounds__(256) void block_scan_write(
    const int* __restrict__ deg, const int* __restrict__ boff,
    int* __restrict__ row_ptr, int* __restrict__ cursor, int n, int total) {
    __shared__ int s[256];
    int t = threadIdx.x;
    int i = blockIdx.x * 256 + t;
    int v = (i < n) ? deg[i] : 0;
    s[t] = v;
    __syncthreads();
    for (int o = 1; o < 256; o <<= 1) {
        int u = (t >= o) ? s[t - o] : 0;
        __syncthreads();
        s[t] += u;
        __syncthreads();
    }
    int excl = s[t] - v + boff[blockIdx.x];
    if (i < n) { row_ptr[i] = excl; cursor[i] = excl; }
    if (blockIdx.x == 0 && t == 0) row_ptr[n] = total;
}

__global__ void place_edges4(const int* __restrict__ dst, const int* __restrict__ src,
                             const int* __restrict__ rel, int* __restrict__ cursor,
                             int* __restrict__ e_srcs, int E) {
    int e = blockIdx.x * 256 + threadIdx.x;
    if (e < E) {
        int p = atomicAdd(&cursor[dst[e] * 4 + rel[e]], 1);
        e_srcs[p] = src[e];
    }
}

// ---------------------------------------------------------------------------
// Layer-0 aggregate: h0 = relu(root[n] + sum_r inv_r * sum_e msg[src, r])
// ---------------------------------------------------------------------------
__global__ __launch_bounds__(256) void aggregate0(
    const unsigned short* __restrict__ rootb,   // [M_PAD,256]
    const unsigned short* __restrict__ msg,     // [M_PAD,1024]
    const int* __restrict__ rp4, const int* __restrict__ e_srcs,
    const float* __restrict__ inv4,
    unsigned short* __restrict__ h_out)         // [M_PAD,256]
{
    int node = blockIdx.x * 4 + (threadIdx.x >> 6);
    if (node >= N_NODES) return;
    int lane = threadIdx.x & 63;
    float4 iv = *(const float4*)&inv4[(size_t)node * 4];

    ushort4 rt = *(const ushort4*)&rootb[(size_t)node * 256 + lane * 4];
    float4 acc = make_float4(bf2f(rt.x), bf2f(rt.y), bf2f(rt.z), bf2f(rt.w));

    #pragma unroll
    for (int r = 0; r < 4; ++r) {
        int lo = rp4[(size_t)node * 4 + r], hi = rp4[(size_t)node * 4 + r + 1];
        float f = (r == 0) ? iv.x : (r == 1) ? iv.y : (r == 2) ? iv.z : iv.w;
        float4 s4 = make_float4(0, 0, 0, 0);
        int e = lo;
        for (; e + 1 < hi; e += 2) {
            ushort4 m0 = *(const ushort4*)&msg[(size_t)e_srcs[e] * 1024 + (r << 8) + lane * 4];
            ushort4 m1 = *(const ushort4*)&msg[(size_t)e_srcs[e + 1] * 1024 + (r << 8) + lane * 4];
            s4.x += bf2f(m0.x) + bf2f(m1.x);
            s4.y += bf2f(m0.y) + bf2f(m1.y);
            s4.z += bf2f(m0.z) + bf2f(m1.z);
            s4.w += bf2f(m0.w) + bf2f(m1.w);
        }
        if (e < hi) {
            ushort4 m0 = *(const ushort4*)&msg[(size_t)e_srcs[e] * 1024 + (r << 8) + lane * 4];
            s4.x += bf2f(m0.x); s4.y += bf2f(m0.y);
            s4.z += bf2f(m0.z); s4.w += bf2f(m0.w);
        }
        acc.x += s4.x * f; acc.y += s4.y * f;
        acc.z += s4.z * f; acc.w += s4.w * f;
    }
    ushort4 o;
    o.x = f2bf(fmaxf(acc.x, 0.f));
    o.y = f2bf(fmaxf(acc.y, 0.f));
    o.z = f2bf(fmaxf(acc.z, 0.f));
    o.w = f2bf(fmaxf(acc.w, 0.f));
    *(ushort4*)&h_out[(size_t)node * 256 + lane * 4] = o;
}

// ---------------------------------------------------------------------------
// Pooling + MLP head
// ---------------------------------------------------------------------------
__global__ __launch_bounds__(256) void pool_kernel(
    const unsigned short* __restrict__ h, const int* __restrict__ batch,
    float* __restrict__ g_feat)
{
    int g = blockIdx.x;
    int t = threadIdx.x;
    __shared__ int s_lo, s_hi;
    if (t == 0) {
        int lo = 0, hi = N_NODES;
        while (lo < hi) { int m = (lo + hi) >> 1; if (batch[m] < g) lo = m + 1; else hi = m; }
        s_lo = lo;
        int lo2 = lo, hi2 = N_NODES;
        while (lo2 < hi2) { int m = (lo2 + hi2) >> 1; if (batch[m] < g + 1) lo2 = m + 1; else hi2 = m; }
        s_hi = lo2;
    }
    __syncthreads();
    int lo = s_lo, hi = s_hi;
    float sum = 0.f, mx = 0.f;   // post-ReLU
    for (int n = lo; n < hi; ++n) {
        float v = bf2f(h[(size_t)n * 256 + t]);
        sum += v;
        mx = fmaxf(mx, v);
    }
    float cnt = (float)(hi - lo);
    g_feat[g * 512 + t]       = sum / fmaxf(cnt, 1.0f);
    g_feat[g * 512 + 256 + t] = (cnt > 0.f) ? mx : 0.f;
}

__global__ __launch_bounds__(128) void mlp_head(
    const float* __restrict__ g_feat,
    const float* __restrict__ fc1_w, const float* __restrict__ fc1_b,
    const float* __restrict__ fc2_w, const float* __restrict__ fc2_b,
    float* __restrict__ out)
{
    __shared__ float gf[512];
    __shared__ float partial[2];
    int g = blockIdx.x, t = threadIdx.x;
    for (int i = t; i < 512; i += 128) gf[i] = g_feat[g * 512 + i];
    __syncthreads();
    float acc = fc1_b[t];
    for (int i = 0; i < 512; ++i) acc += gf[i] * fc1_w[i * 128 + t];
    float h1 = fmaxf(acc, 0.f);
    float v = h1 * fc2_w[t];
    #pragma unroll
    for (int off = 32; off > 0; off >>= 1) v += __shfl_down(v, off);
    if ((t & 63) == 0) partial[t >> 6] = v;
    __syncthreads();
    if (t == 0) {
        float s = partial[0] + partial[1] + fc2_b[0];
        out[g] = 1.0f / (1.0f + expf(-s));
    }
}

// ---------------------------------------------------------------------------
// Launch
// ---------------------------------------------------------------------------
extern "C" void kernel_launch(void* const* d_in, const int* in_sizes, int n_in,
                              void* d_out, int out_size, void* d_ws, size_t ws_size,
                              hipStream_t stream) {
    const float* x          = (const float*)d_in[0];
    const int*   edge_index = (const int*)d_in[1];
    const int*   edge_attr  = (const int*)d_in[2];
    const int*   batch      = (const int*)d_in[3];
    const float* w0         = (const float*)d_in[4];
    const float* root0      = (const float*)d_in[5];
    const float* b0         = (const float*)d_in[6];
    const float* w_rest     = (const float*)d_in[7];
    const float* root_rest  = (const float*)d_in[8];
    const float* b_rest     = (const float*)d_in[9];
    const float* fc1_w      = (const float*)d_in[10];
    const float* fc1_b      = (const float*)d_in[11];
    const float* fc2_w      = (const float*)d_in[12];
    const float* fc2_b      = (const float*)d_in[13];
    float* out = (float*)d_out;

    const int* e_src = edge_index;
    const int* e_dst = edge_index + N_EDGES;

    char* p = (char*)d_ws;
    auto alloc = [&](size_t bytes) { char* q = p; p += (bytes + 255) & ~(size_t)255; return q; };
    unsigned short* x_bf   = (unsigned short*)alloc((size_t)M_PAD * D_IN * 2);   // 92 MB
    unsigned short* msgbuf = (unsigned short*)alloc((size_t)M_PAD * 1024 * 2);   // 123 MB
    unsigned short* hA     = (unsigned short*)alloc((size_t)M_PAD * 256 * 2);    // 31 MB
    unsigned short* hB     = (unsigned short*)alloc((size_t)M_PAD * 256 * 2);    // 31 MB
    unsigned short* Wt0    = (unsigned short*)alloc((size_t)N_TOT * D_IN * 2);
    unsigned short* WtR    = (unsigned short*)alloc((size_t)5 * 256 * N_TOT * 2);
    float*          ebias  = (float*)alloc(N_TOT * 4);
    float*          inv4   = (float*)alloc((size_t)N_NODES * 4 * 4);
    float*          g_feat = (float*)alloc((size_t)N_GRAPHS * 512 * 4);
    int*            deg4   = (int*)alloc((size_t)N_NODES * 4 * 4);
    int*            rp4    = (int*)alloc(((size_t)N_NODES * 4 + 1) * 4);
    int*            cursor4= (int*)alloc((size_t)N_NODES * 4 * 4);
    int*            bsum   = (int*)alloc(1024 * 4);
    int*            boff   = (int*)alloc(1024 * 4);
    int*            e_srcs = (int*)alloc((size_t)N_EDGES * 4);

    const int n4 = N_NODES * 4;                 // 240000
    const int nscan4 = cdiv(n4, 256);           // 938

    // --- prep ---
    hipMemsetAsync(deg4, 0, (size_t)n4 * 4, stream);
    convert_x<<<cdiv(M_PAD * D_IN / 4, 256), 256, 0, stream>>>(x, x_bf);
    pack_w0<<<cdiv(N_TOT * D_IN, 256), 256, 0, stream>>>(root0, w0, Wt0);
    pack_wr<<<cdiv(5 * 256 * N_TOT, 256), 256, 0, stream>>>(root_rest, w_rest, WtR);
    build_bias<<<cdiv(N_TOT, 256), 256, 0, stream>>>(b0, ebias);
    deg4_count<<<cdiv(N_EDGES, 256), 256, 0, stream>>>(e_dst, edge_attr, deg4, N_EDGES);
    invert4<<<cdiv(n4, 256), 256, 0, stream>>>(deg4, inv4, n4);
    block_sum<<<nscan4, 256, 0, stream>>>(deg4, bsum, n4);
    scan_bsum<<<1, 1024, 0, stream>>>(bsum, boff, nscan4);
    block_scan_write<<<nscan4, 256, 0, stream>>>(deg4, boff, rp4, cursor4, n4, N_EDGES);
    place_edges4<<<cdiv(N_EDGES, 256), 256, 0, stream>>>(e_dst, e_src, edge_attr,
                                                         cursor4, e_srcs, N_EDGES);

    // --- layer 0: transform-first GEMM, XCD-swizzled flat grid ---
    gemm_l0<<<2345, 512, 0, stream>>>(x_bf, Wt0, ebias, hB, msgbuf, D_IN);
    aggregate0<<<cdiv(N_NODES, 4), 256, 0, stream>>>(hB, msgbuf, rp4, e_srcs, inv4, hA);

    // --- layers 1..5: fused gather+mean+GEMM (W direct from L2) ---
    unsigned short* cur = hA;
    unsigned short* nxt = hB;
    for (int L = 1; L < N_LAYERS; ++L) {
        rgcn_layer<<<M_PAD / BM_L, 512, 0, stream>>>(
            cur, WtR + (size_t)(L - 1) * 256 * N_TOT, b_rest + (size_t)(L - 1) * 256,
            rp4, e_srcs, inv4, nxt);
        unsigned short* t = cur; cur = nxt; nxt = t;
    }
    // final h in cur

    pool_kernel<<<N_GRAPHS, 256, 0, stream>>>(cur, batch, g_feat);
    mlp_head<<<N_GRAPHS, 128, 0, stream>>>(g_feat, fc1_w, fc1_b, fc2_w, fc2_b, out);
}